// Round 11
// baseline (109.379 us; speedup 1.0000x reference)
//
#include <hip/hip_runtime.h>

typedef unsigned short ushort_t;
typedef __attribute__((ext_vector_type(8))) short bf16x8;
typedef __attribute__((ext_vector_type(4))) float f32x4;

__device__ __forceinline__ unsigned short f2bf(float f) {
  union { float f; unsigned u; } x; x.f = f;
  unsigned r = x.u + 0x7FFFu + ((x.u >> 16) & 1u);   // round-to-nearest-even
  return (unsigned short)(r >> 16);
}

// ---------------- chain part 1: g[b][q][y][c][z] = sum_r f1[b,q,r,y]*lf[c,r,z]
__global__ void chain_g_kernel(const float* __restrict__ f1,
                               const float* __restrict__ lf,
                               float* __restrict__ g) {
  int idx = blockIdx.x * 256 + threadIdx.x;           // 32768 total
  int z = idx & 7, c = (idx >> 3) & 3, y = (idx >> 5) & 7,
      q = (idx >> 8) & 15, b = idx >> 12;
  float s = 0.f;
  #pragma unroll
  for (int r = 0; r < 16; ++r)
    s += f1[((b * 16 + q) * 16 + r) * 8 + y] * lf[(c * 16 + r) * 8 + z];
  g[idx] = s;
}

// ---------------- chain part 2: chainT[o][k] = sum_q f0[a,p,q,x]*g[b,q,y,c,z]
// o = (x*8+y)*8+z ; k = ((a*8+b)*4+c)*4+p
__global__ void chain_kernel(const float* __restrict__ f0,
                             const float* __restrict__ g,
                             ushort_t* __restrict__ chainT) {
  int idx = blockIdx.x * 256 + threadIdx.x;           // 524288 total = o*1024+k
  int k = idx & 1023, o = idx >> 10;
  int p = k & 3, c = (k >> 2) & 3, b = (k >> 4) & 7, a = k >> 7;
  int z = o & 7, y = (o >> 3) & 7, x = o >> 6;
  float s = 0.f;
  #pragma unroll
  for (int q = 0; q < 16; ++q)
    s += f0[((a * 4 + p) * 16 + q) * 8 + x] *
         g[(((b * 16 + q) * 8 + y) * 4 + c) * 8 + z];
  chainT[idx] = f2bf(s);
}

// ---------------- FUSED conv+GEMM, 2 blocks/CU.
// block = 128 pixels (n, 4 h-rows, 32 w) x 256 o (nh half). Grid 512 = 2/CU.
// Per step kt: p1 {MFMA(kt)} | p2a {STAGE_B(kt+1) || conv(kt+1)->As[(kt+1)&1]} |
//              p2b {Is<-in(kt+2), issue in(kt+3), vmcnt(3)}.
// Sync: producer-side vmcnt pre-barrier; stage only after last-read phase closed.
#define AS1 __attribute__((address_space(1)))
#define AS3 __attribute__((address_space(3)))
#define BARRIER  __builtin_amdgcn_s_barrier()
#define LGKMCNT0 asm volatile("s_waitcnt lgkmcnt(0)" ::: "memory")
#define VMCNT3   asm volatile("s_waitcnt vmcnt(3)" ::: "memory")
#define VMCNT0   asm volatile("s_waitcnt vmcnt(0)" ::: "memory")

__global__ __launch_bounds__(512, 4) void fused_kernel(const float* __restrict__ in,
                                                       const float* __restrict__ sf,
                                                       const ushort_t* __restrict__ chainT,
                                                       const float* __restrict__ bias,
                                                       float* __restrict__ out) {
  __shared__ __align__(16) ushort_t Bs[16384];      // 32 KB [256 rows][64 k] swizzled
  __shared__ __align__(16) ushort_t As[2][8192];    // 2x16 KB [128 rows][64 k] swizzled
  __shared__ __align__(16) float Is[3072];          // 16ch x 6r x 32w (no pad; edges via cndmask)

  int tid = threadIdx.x;
  int bid = blockIdx.x;                             // 512 blocks
  int wg = (bid & 7) * 64 + (bid >> 3);             // XCD swizzle; (pix,nh) pairs same XCD
  int pix = wg >> 1, nh = wg & 1;
  int n = pix >> 3, hq = pix & 7, h0 = hq * 4;

  int lane = tid & 63, wv = tid >> 6;
  int wm = (wv >> 2) * 64, wn = (wv & 3) * 64;      // per-wave 64M x 64N
  int lr = lane & 15, kg = lane >> 4;
  int kph0 = ((kg * 8) ^ ((lane & 7) * 8));
  int kph1 = ((32 + kg * 8) ^ ((lane & 7) * 8));

  // B staging (proven pattern): source chunk pre-swizzled, LDS linear
  int srow = tid >> 3;
  int scol = ((tid & 7) ^ (srow & 7)) * 8;
  const ushort_t* sB = chainT + (size_t)(nh * 256 + srow) * 1024 + scol;

  // conv mapping
  int cw = tid & 31, hp = (tid >> 5) & 1, ch2 = wv;
  int aswz = (ch2 ^ (cw & 7)) * 8;

  // input staging decode: 3 float2/thread = 16ch x 6r x 16 float2 exactly
  int isrc[3], ild[3], izer[3];
  #pragma unroll
  for (int i = 0; i < 3; ++i) {
    int e = tid + i * 512;
    int ch = e / 96, rem = e % 96, r = rem >> 4, w2 = rem & 15;
    int hh = h0 - 1 + r;
    int hcl = hh < 0 ? 0 : (hh > 31 ? 31 : hh);
    izer[i] = (hh < 0) | (hh > 31);
    isrc[i] = ch * 1024 + hcl * 32 + w2 * 2;
    ild[i]  = ch * 192 + r * 32 + w2 * 2;
  }
  const float* inb = in + (size_t)n * 262144;
  float2 rin[3];

  float sfr[36];
  #pragma unroll
  for (int i = 0; i < 36; ++i)
    sfr[i] = __int_as_float(__builtin_amdgcn_readfirstlane(__float_as_int(sf[i])));

  float bv[4];
  #pragma unroll
  for (int nf = 0; nf < 4; ++nf) bv[nf] = bias[nh * 256 + wn + nf * 16 + lr];

  f32x4 acc[4][4];
  #pragma unroll
  for (int i = 0; i < 4; ++i)
    #pragma unroll
    for (int j = 0; j < 4; ++j) acc[i][j] = (f32x4){0.f, 0.f, 0.f, 0.f};

#define ISSUE_IN(KT)                                                                     \
  _Pragma("unroll")                                                                      \
  for (int i = 0; i < 3; ++i)                                                            \
    rin[i] = *(const float2*)&inb[(size_t)(KT) * 16384 + isrc[i]];

#define WRITE_IN                                                                         \
  _Pragma("unroll")                                                                      \
  for (int i = 0; i < 3; ++i) {                                                          \
    float2 v = rin[i];                                                                   \
    if (izer[i]) { v.x = 0.f; v.y = 0.f; }                                               \
    *(float2*)&Is[ild[i]] = v;                                                           \
  }

#define STAGE_B(KT)                                                                      \
  _Pragma("unroll")                                                                      \
  for (int l = 0; l < 4; ++l)                                                            \
    __builtin_amdgcn_global_load_lds(                                                    \
        (const AS1 void*)(sB + (size_t)l * 65536 + (KT) * 64),                           \
        (AS3 void*)&Bs[l * 4096 + tid * 8], 16, 0, 0);

#define CONV(AB)                                                                         \
  {                                                                                      \
    unsigned pw[2][4];                                                                   \
    _Pragma("unroll")                                                                    \
    for (int b = 0; b < 2; ++b) {                                                        \
      const float* isp = &Is[(ch2 * 2 + b) * 192];                                       \
      float tap[4][3];                                                                   \
      _Pragma("unroll")                                                                  \
      for (int r4 = 0; r4 < 4; ++r4) {                                                   \
        int rb = (hp * 2 + r4) * 32;                                                     \
        float lv = isp[rb + ((cw == 0) ? 0 : cw - 1)];                                   \
        float mv = isp[rb + cw];                                                         \
        float rv = isp[rb + ((cw == 31) ? 31 : cw + 1)];                                 \
        tap[r4][0] = (cw == 0) ? 0.f : lv;                                               \
        tap[r4][1] = mv;                                                                 \
        tap[r4][2] = (cw == 31) ? 0.f : rv;                                              \
      }                                                                                  \
      _Pragma("unroll")                                                                  \
      for (int j = 0; j < 2; ++j) {                                                      \
        float s0 = 0.f, s1 = 0.f, s2 = 0.f, s3 = 0.f;                                    \
        _Pragma("unroll")                                                                \
        for (int dr = 0; dr < 3; ++dr)                                                   \
          _Pragma("unroll")                                                              \
          for (int dt = 0; dt < 3; ++dt) {                                               \
            float tv = tap[j + dr][dt];                                                  \
            s0 += tv * sfr[0 * 9 + dr * 3 + dt];                                         \
            s1 += tv * sfr[1 * 9 + dr * 3 + dt];                                         \
            s2 += tv * sfr[2 * 9 + dr * 3 + dt];                                         \
            s3 += tv * sfr[3 * 9 + dr * 3 + dt];                                         \
          }                                                                              \
        pw[j][b * 2 + 0] = (unsigned)f2bf(s0) | ((unsigned)f2bf(s1) << 16);              \
        pw[j][b * 2 + 1] = (unsigned)f2bf(s2) | ((unsigned)f2bf(s3) << 16);              \
      }                                                                                  \
    }                                                                                    \
    _Pragma("unroll")                                                                    \
    for (int j = 0; j < 2; ++j) {                                                        \
      uint4 pk; pk.x = pw[j][0]; pk.y = pw[j][1]; pk.z = pw[j][2]; pk.w = pw[j][3];      \
      int row = (hp * 2 + j) * 32 + cw;                                                  \
      *(uint4*)&As[AB][row * 64 + aswz] = pk;                                            \
    }                                                                                    \
  }

#define MFMA_PHASE(AB)                                                                   \
  _Pragma("unroll")                                                                      \
  for (int ks = 0; ks < 2; ++ks) {                                                       \
    int kph = ks ? kph1 : kph0;                                                          \
    bf16x8 af[4], bq[4];                                                                 \
    _Pragma("unroll")                                                                    \
    for (int mf = 0; mf < 4; ++mf)                                                       \
      af[mf] = *(const bf16x8*)&As[AB][(wm + mf * 16 + lr) * 64 + kph];                  \
    _Pragma("unroll")                                                                    \
    for (int nq = 0; nq < 4; ++nq)                                                       \
      bq[nq] = *(const bf16x8*)&Bs[(wn + nq * 16 + lr) * 64 + kph];                      \
    __builtin_amdgcn_s_setprio(1);                                                       \
    _Pragma("unroll")                                                                    \
    for (int mf = 0; mf < 4; ++mf)                                                       \
      _Pragma("unroll")                                                                  \
      for (int nq = 0; nq < 4; ++nq)                                                     \
        acc[mf][nq] = __builtin_amdgcn_mfma_f32_16x16x32_bf16(                           \
            af[mf], bq[nq], acc[mf][nq], 0, 0, 0);                                       \
    __builtin_amdgcn_s_setprio(0);                                                       \
  }

  // ---- prologue
  ISSUE_IN(0)
  WRITE_IN                                          // compiler waits in(0)
  ISSUE_IN(1)
  LGKMCNT0; BARRIER;                                // Is(0) visible
  CONV(0)                                           // Is(0) -> As[0]
  STAGE_B(0)
  LGKMCNT0; BARRIER;                                // conv reads + As[0] writes done
  WRITE_IN                                          // Is = in(1)  (vmcnt(4), keeps B in flight)
  ISSUE_IN(2)
  LGKMCNT0; VMCNT3; BARRIER;                        // As[0], Bs(0), Is(1) certified

  #pragma unroll 1
  for (int I = 0; I < 8; ++I) {
    // ==== kt = 2I (even) ====
    MFMA_PHASE(0)
    LGKMCNT0; BARRIER;
    STAGE_B(2 * I + 1)
    CONV(1)                                         // Is(2I+1) -> As[1]
    LGKMCNT0; BARRIER;
    if (I < 7) { WRITE_IN ISSUE_IN(2 * I + 3) }     // Is = in(2I+2)
    LGKMCNT0;
    if (I < 7) { VMCNT3; } else { VMCNT0; }
    BARRIER;
    // ==== kt = 2I+1 (odd) ====
    MFMA_PHASE(1)
    LGKMCNT0; BARRIER;
    if (I < 7) { STAGE_B(2 * I + 2) CONV(0) }       // Is(2I+2) -> As[0]
    LGKMCNT0; BARRIER;
    if (I < 7) { WRITE_IN }                         // Is = in(2I+3)
    if (I < 6) { ISSUE_IN(2 * I + 4) }
    LGKMCNT0;
    if (I < 6) { VMCNT3; } else { VMCNT0; }
    BARRIER;
  }

  // ---- epilogue: lane holds D[m=kg*4+r][o=lr] per 16x16 frag
  #pragma unroll
  for (int mf = 0; mf < 4; ++mf)
    #pragma unroll
    for (int nf = 0; nf < 4; ++nf) {
      int mloc = hq * 128 + wm + mf * 16 + kg * 4;
      int o = nh * 256 + wn + nf * 16 + lr;
      f32x4 vv = acc[mf][nf];
      vv[0] += bv[nf]; vv[1] += bv[nf]; vv[2] += bv[nf]; vv[3] += bv[nf];
      *(f32x4*)&out[(size_t)n * 524288 + (size_t)o * 1024 + mloc] = vv;
    }
}

extern "C" void kernel_launch(void* const* d_in, const int* in_sizes, int n_in,
                              void* d_out, int out_size, void* d_ws, size_t ws_size,
                              hipStream_t stream) {
  (void)in_sizes; (void)n_in; (void)out_size; (void)ws_size;
  const float* in   = (const float*)d_in[0];
  const float* sf   = (const float*)d_in[1];
  const float* f0   = (const float*)d_in[2];
  const float* f1   = (const float*)d_in[3];
  const float* lf   = (const float*)d_in[4];
  const float* bias = (const float*)d_in[5];
  float* out = (float*)d_out;

  char* ws = (char*)d_ws;
  ushort_t* chainT = (ushort_t*)ws;                 // 1 MB
  float*    g      = (float*)(ws + 1048576);        // 128 KB

  hipLaunchKernelGGL(chain_g_kernel, dim3(128),  dim3(256), 0, stream, f1, lf, g);
  hipLaunchKernelGGL(chain_kernel,   dim3(2048), dim3(256), 0, stream, f0, g, chainT);
  hipLaunchKernelGGL(fused_kernel,   dim3(512),  dim3(512), 0, stream, in, sf, chainT, bias, out);
}

// Round 12
// 80.377 us; speedup vs baseline: 1.3608x; 1.3608x over previous
//
#include <hip/hip_runtime.h>

typedef unsigned short ushort_t;
typedef __attribute__((ext_vector_type(8))) short bf16x8;
typedef __attribute__((ext_vector_type(8))) unsigned short ushort8;
typedef __attribute__((ext_vector_type(4))) float f32x4;

__device__ __forceinline__ unsigned short f2bf(float f) {
  union { float f; unsigned u; } x; x.f = f;
  unsigned r = x.u + 0x7FFFu + ((x.u >> 16) & 1u);   // round-to-nearest-even
  return (unsigned short)(r >> 16);
}

// ---------------- chain part 1: g[b][q][y][c][z] = sum_r f1[b,q,r,y]*lf[c,r,z]
__global__ void chain_g_kernel(const float* __restrict__ f1,
                               const float* __restrict__ lf,
                               float* __restrict__ g) {
  int idx = blockIdx.x * 256 + threadIdx.x;           // 32768 total
  int z = idx & 7, c = (idx >> 3) & 3, y = (idx >> 5) & 7,
      q = (idx >> 8) & 15, b = idx >> 12;
  float s = 0.f;
  #pragma unroll
  for (int r = 0; r < 16; ++r)
    s += f1[((b * 16 + q) * 16 + r) * 8 + y] * lf[(c * 16 + r) * 8 + z];
  g[idx] = s;
}

// ---------------- chain part 2: chainT[o][k] = sum_q f0[a,p,q,x]*g[b,q,y,c,z]
// o = (x*8+y)*8+z ; k = ((a*8+b)*4+c)*4+p
__global__ void chain_kernel(const float* __restrict__ f0,
                             const float* __restrict__ g,
                             ushort_t* __restrict__ chainT) {
  int idx = blockIdx.x * 256 + threadIdx.x;           // 524288 total = o*1024+k
  int k = idx & 1023, o = idx >> 10;
  int p = k & 3, c = (k >> 2) & 3, b = (k >> 4) & 7, a = k >> 7;
  int z = o & 7, y = (o >> 3) & 7, x = o >> 6;
  float s = 0.f;
  #pragma unroll
  for (int q = 0; q < 16; ++q)
    s += f0[((a * 4 + p) * 16 + q) * 8 + x] *
         g[(((b * 16 + q) * 8 + y) * 4 + c) * 8 + z];
  chainT[idx] = f2bf(s);
}

// ---------------- depthwise 3x3 conv -> t[m][k] bf16 (K-contiguous)
// block = (n, h-quad, channel-quarter). grid = 32*8*4 = 1024 blocks.
__global__ __launch_bounds__(256) void conv_kernel(const float* __restrict__ in,
                                                   const float* __restrict__ sf,
                                                   ushort_t* __restrict__ t) {
  __shared__ float in_lds[64][244];
  __shared__ float sf_l[36];
  int bid = blockIdx.x;
  int cq = bid & 3, h4 = (bid >> 2) & 7, n = bid >> 5;
  int h0 = h4 * 4;
  int tid = threadIdx.x;
  if (tid < 36) sf_l[tid] = sf[tid];
  for (int e = tid; e < 384; e += 256) {
    int ch = e / 6, r = e % 6;
    in_lds[ch][r * 40 + 3] = 0.f;
    in_lds[ch][r * 40 + 36] = 0.f;
  }
  const float* inb = in + ((size_t)n * 256 + cq * 64) * 1024;
  #pragma unroll
  for (int i = 0; i < 12; ++i) {
    int e = tid + i * 256;
    int ch = e / 48, rem = e % 48;
    int r = rem >> 3, w4 = rem & 7;
    int hh = h0 - 1 + r;
    float4 v = make_float4(0.f, 0.f, 0.f, 0.f);
    if (hh >= 0 && hh < 32)
      v = *(const float4*)&inb[(size_t)ch * 1024 + hh * 32 + w4 * 4];
    *(float4*)&in_lds[ch][r * 40 + 4 + w4 * 4] = v;
  }
  __syncthreads();
  float sfr[36];
  #pragma unroll
  for (int i = 0; i < 36; ++i) sfr[i] = sf_l[i];
  int w = tid >> 3, gg = tid & 7;
  size_t m0 = (size_t)n * 1024 + (size_t)h0 * 32 + w;
  #pragma unroll
  for (int j = 0; j < 4; ++j) {
    float acc[4][2][4];
    #pragma unroll
    for (int b = 0; b < 2; ++b) {
      int ch = j * 16 + gg * 2 + b;
      float vals[6][3];
      #pragma unroll
      for (int r = 0; r < 6; ++r)
        #pragma unroll
        for (int dw = 0; dw < 3; ++dw)
          vals[r][dw] = in_lds[ch][r * 40 + 3 + w + dw];
      #pragma unroll
      for (int hh = 0; hh < 4; ++hh)
        #pragma unroll
        for (int p = 0; p < 4; ++p) {
          float s = 0.f;
          #pragma unroll
          for (int dr = 0; dr < 3; ++dr)
            #pragma unroll
            for (int dw = 0; dw < 3; ++dw)
              s += vals[hh + dr][dw] * sfr[p * 9 + dr * 3 + dw];
          acc[hh][b][p] = s;
        }
    }
    #pragma unroll
    for (int hh = 0; hh < 4; ++hh) {
      ushort8 outv;
      #pragma unroll
      for (int b = 0; b < 2; ++b)
        #pragma unroll
        for (int p = 0; p < 4; ++p) outv[b * 4 + p] = f2bf(acc[hh][b][p]);
      *(ushort8*)&t[(m0 + hh * 32) * 1024 + (size_t)(cq * 256 + j * 64 + gg * 8)] = outv;
    }
  }
}

// ---------------- GEMM: out[m][o] = sum_k t[m][k]*chainT[o][k] + bias[o]
// 256x256 tile, BK=64, 8 waves (2Mx4N), 8-phase schedule, counted vmcnt,
// XOR-swizzled LDS, raw s_barrier, setprio.
// SYNC (sound, round-6/7 rules):
//  (RAW) producer-side VMCNT before the barrier that releases readers:
//        p3 pre-close VMCNT4 retires {A1k3,B1k1}; p7 retires {A0k2,B0k2}.
//  (WAR) all ds_reads of a buffer happen in p0/p1 (p4/p5), forced serviced via
//        LGKMCNT0 after the mid-barrier; its re-stage comes >=1 closing barrier later.
#define AS1 __attribute__((address_space(1)))
#define AS3 __attribute__((address_space(3)))
#define BARRIER  __builtin_amdgcn_s_barrier()
#define LGKMCNT0 asm volatile("s_waitcnt lgkmcnt(0)" ::: "memory")
#define VMCNT4   asm volatile("s_waitcnt vmcnt(4)" ::: "memory")
#define VMCNT0   asm volatile("s_waitcnt vmcnt(0)" ::: "memory")

__global__ __launch_bounds__(512, 2) void gemm_kernel(const ushort_t* __restrict__ tA,
                                                      const ushort_t* __restrict__ tB,
                                                      const float* __restrict__ bias,
                                                      float* __restrict__ out) {
  __shared__ __align__(16) ushort_t smem[65536];   // 128 KB: As[2][16384] | Bs[2][16384]
  int tid = threadIdx.x;
  int bid = blockIdx.x;                            // 256 blocks
  int wg = (bid & 7) * 32 + (bid >> 3);            // bijective XCD swizzle (256%8==0)
  int tile_m = (wg >> 1) * 256;
  int tile_n = (wg & 1) * 256;

  int lane = tid & 63, wv = tid >> 6;
  int wm2 = wv >> 2, wn4 = wv & 3;
  int lr = lane & 15, kg = lane >> 4;
  int kph0 = ((kg * 8) ^ ((lane & 7) * 8));
  int kph1 = ((32 + kg * 8) ^ ((lane & 7) * 8));
  int arow = wm2 * 128 + lr;
  int brow = wn4 * 64 + lr;

  int srow = tid >> 3;
  int scol = ((tid & 7) ^ (srow & 7)) * 8;
  const ushort_t* sA = tA + (size_t)(tile_m + srow) * 1024 + scol;
  const ushort_t* sB = tB + (size_t)(tile_n + srow) * 1024 + scol;

#define STAGE_A(buf, koff, h)                                                                  \
  __builtin_amdgcn_global_load_lds((const AS1 void*)(sA + (size_t)((h)*128) * 1024 + (koff)),  \
      (AS3 void*)&smem[(buf)*16384 + (h)*8192 + tid*8], 16, 0, 0);                             \
  __builtin_amdgcn_global_load_lds((const AS1 void*)(sA + (size_t)((h)*128+64) * 1024 + (koff)),\
      (AS3 void*)&smem[(buf)*16384 + (h)*8192 + 4096 + tid*8], 16, 0, 0);
#define STAGE_B(buf, koff, h)                                                                  \
  __builtin_amdgcn_global_load_lds((const AS1 void*)(sB + (size_t)((h)*128) * 1024 + (koff)),  \
      (AS3 void*)&smem[32768 + (buf)*16384 + (h)*8192 + tid*8], 16, 0, 0);                     \
  __builtin_amdgcn_global_load_lds((const AS1 void*)(sB + (size_t)((h)*128+64) * 1024 + (koff)),\
      (AS3 void*)&smem[32768 + (buf)*16384 + (h)*8192 + 4096 + tid*8], 16, 0, 0);

#define READ_A(dst, mbase, buf)                                                                \
  _Pragma("unroll")                                                                            \
  for (int mf = 0; mf < 4; ++mf) {                                                             \
    dst[mf][0] = *(const bf16x8*)&smem[(buf)*16384 + (arow + (mbase) + mf*16)*64 + kph0];      \
    dst[mf][1] = *(const bf16x8*)&smem[(buf)*16384 + (arow + (mbase) + mf*16)*64 + kph1];      \
  }
#define READ_B(dst, nbase, buf)                                                                \
  _Pragma("unroll")                                                                            \
  for (int nf = 0; nf < 2; ++nf) {                                                             \
    dst[nf][0] = *(const bf16x8*)&smem[32768 + (buf)*16384 + (brow + (nbase) + nf*16)*64 + kph0];\
    dst[nf][1] = *(const bf16x8*)&smem[32768 + (buf)*16384 + (brow + (nbase) + nf*16)*64 + kph1];\
  }
#define Q_MFMA(AF, BF, MB, NB)                                                                 \
  __builtin_amdgcn_s_setprio(1);                                                              \
  _Pragma("unroll")                                                                            \
  for (int mf = 0; mf < 4; ++mf)                                                               \
    _Pragma("unroll")                                                                          \
    for (int nf = 0; nf < 2; ++nf)                                                             \
      _Pragma("unroll")                                                                        \
      for (int ks = 0; ks < 2; ++ks)                                                           \
        acc[(MB) + mf][(NB) + nf] = __builtin_amdgcn_mfma_f32_16x16x32_bf16(                   \
            AF[mf][ks], BF[nf][ks], acc[(MB) + mf][(NB) + nf], 0, 0, 0);                       \
  __builtin_amdgcn_s_setprio(0);

  f32x4 acc[8][4];
  #pragma unroll
  for (int i = 0; i < 8; ++i)
    #pragma unroll
    for (int j = 0; j < 4; ++j) acc[i][j] = (f32x4){0.f, 0.f, 0.f, 0.f};

  bf16x8 a1[4][2], a2[4][2], b1[2][2], b2[2][2];

  // prologue: kt0 (buf0) fully + kt1 A halves (buf1); VMCNT4 retires exactly
  // buf0's 8 loads producer-side BEFORE the barrier releases readers.
  STAGE_A(0, 0, 0) STAGE_A(0, 0, 1) STAGE_B(0, 0, 0) STAGE_B(0, 0, 1)
  STAGE_A(1, 64, 0) STAGE_A(1, 64, 1)
  VMCNT4; BARRIER;

  // FIFO at p3-end: [A1k3(4 oldest), B1k1(4), A0k2(4)] -> VMCNT4 retires buf1's 8.
  // FIFO at p7-end: [A0k2(4), B0k2(4), A1k3(4)]        -> VMCNT4 retires buf0's 8.
#define ITER(I_, FULL)                                                                         \
  {                                                                                            \
    int k1 = (2*(I_)+1)*64, k2 = (2*(I_)+2)*64, k3 = (2*(I_)+3)*64;                            \
    /* p0: all buf0 A reads + b1 (DMA certified by prev p7/prologue) */                        \
    READ_A(a1, 0, 0) READ_A(a2, 64, 0) READ_B(b1, 0, 0)                                        \
    STAGE_B(1, k1, 0) BARRIER; LGKMCNT0;                                                       \
    Q_MFMA(a1, b1, 0, 0) BARRIER;                                                              \
    /* p1 */                                                                                   \
    READ_B(b2, 32, 0) STAGE_B(1, k1, 1) BARRIER; LGKMCNT0;                                     \
    Q_MFMA(a1, b2, 0, 2) BARRIER;                                                              \
    /* p2 */                                                                                   \
    if (FULL) { STAGE_A(0, k2, 0) } BARRIER;                                                   \
    Q_MFMA(a2, b2, 4, 2) BARRIER;                                                              \
    /* p3: certify buf1 DMA (A1k3 prev-iter + B1k1 this-iter) pre-close */                     \
    if (FULL) { STAGE_A(0, k2, 1) } BARRIER;                                                   \
    Q_MFMA(a2, b1, 4, 0)                                                                       \
    if (FULL) { VMCNT4; } else { VMCNT0; }                                                     \
    BARRIER;                                                                                   \
    /* p4: all buf1 reads */                                                                   \
    READ_A(a1, 0, 1) READ_A(a2, 64, 1) READ_B(b1, 0, 1)                                        \
    if (FULL) { STAGE_B(0, k2, 0) } BARRIER; LGKMCNT0;                                         \
    Q_MFMA(a1, b1, 0, 0) BARRIER;                                                              \
    /* p5 */                                                                                   \
    READ_B(b2, 32, 1) if (FULL) { STAGE_B(0, k2, 1) } BARRIER; LGKMCNT0;                       \
    Q_MFMA(a1, b2, 0, 2) BARRIER;                                                              \
    /* p6 */                                                                                   \
    if (FULL) { STAGE_A(1, k3, 0) } BARRIER;                                                   \
    Q_MFMA(a2, b2, 4, 2) BARRIER;                                                              \
    /* p7: certify next-iter buf0 DMA (A0k2+B0k2) pre-close */                                 \
    if (FULL) { STAGE_A(1, k3, 1) } BARRIER;                                                   \
    Q_MFMA(a2, b1, 4, 0)                                                                       \
    if (FULL) { VMCNT4; }                                                                      \
    BARRIER;                                                                                   \
  }

  for (int I = 0; I < 7; ++I) ITER(I, 1)
  ITER(7, 0)
#undef ITER

  // epilogue: lane holds D[m=kg*4+r][o=lr] per 16x16 frag
  #pragma unroll
  for (int mf = 0; mf < 8; ++mf)
    #pragma unroll
    for (int nf = 0; nf < 4; ++nf) {
      int m = tile_m + wm2 * 128 + mf * 16 + kg * 4;
      int o = tile_n + wn4 * 64 + nf * 16 + lr;
      float bv = bias[o];
      f32x4 v = acc[mf][nf];
      v[0] += bv; v[1] += bv; v[2] += bv; v[3] += bv;
      *(f32x4*)&out[(size_t)(m >> 10) * 524288 + (size_t)o * 1024 + (size_t)(m & 1023)] = v;
    }
}

extern "C" void kernel_launch(void* const* d_in, const int* in_sizes, int n_in,
                              void* d_out, int out_size, void* d_ws, size_t ws_size,
                              hipStream_t stream) {
  (void)in_sizes; (void)n_in; (void)out_size; (void)ws_size;
  const float* in   = (const float*)d_in[0];
  const float* sf   = (const float*)d_in[1];
  const float* f0   = (const float*)d_in[2];
  const float* f1   = (const float*)d_in[3];
  const float* lf   = (const float*)d_in[4];
  const float* bias = (const float*)d_in[5];
  float* out = (float*)d_out;

  char* ws = (char*)d_ws;
  ushort_t* t      = (ushort_t*)ws;                          // 64 MB
  ushort_t* chainT = (ushort_t*)(ws + 67108864);             // 1 MB
  float*    g      = (float*)(ws + 67108864 + 1048576);      // 128 KB

  hipLaunchKernelGGL(chain_g_kernel, dim3(128),  dim3(256), 0, stream, f1, lf, g);
  hipLaunchKernelGGL(chain_kernel,   dim3(2048), dim3(256), 0, stream, f0, g, chainT);
  hipLaunchKernelGGL(conv_kernel,    dim3(1024), dim3(256), 0, stream, in, sf, t);
  hipLaunchKernelGGL(gemm_kernel,    dim3(256),  dim3(512), 0, stream, t, chainT, bias, out);
}

// Round 13
// 76.908 us; speedup vs baseline: 1.4222x; 1.0451x over previous
//
#include <hip/hip_runtime.h>

typedef unsigned short ushort_t;
typedef __attribute__((ext_vector_type(8))) short bf16x8;
typedef __attribute__((ext_vector_type(8))) unsigned short ushort8;
typedef __attribute__((ext_vector_type(4))) float f32x4;

__device__ __forceinline__ unsigned short f2bf(float f) {
  union { float f; unsigned u; } x; x.f = f;
  unsigned r = x.u + 0x7FFFu + ((x.u >> 16) & 1u);   // round-to-nearest-even
  return (unsigned short)(r >> 16);
}

// ---------------- fused chain: block = one o (512 blocks x 256 thr)
// gs[b][q][c] = sum_r f1[b,q,r,y]*lf[c,r,z]  (512 floats, LDS)
// chainT[o][k] = sum_q f0[a,p,q,x]*gs[b,q,c],  k=((a*8+b)*4+c)*4+p
__global__ __launch_bounds__(256) void chain_kernel(const float* __restrict__ f0,
                                                    const float* __restrict__ f1,
                                                    const float* __restrict__ lf,
                                                    ushort_t* __restrict__ chainT) {
  __shared__ float gs[512];
  int o = blockIdx.x;
  int z = o & 7, y = (o >> 3) & 7, x = o >> 6;
  int tid = threadIdx.x;
  #pragma unroll
  for (int i = 0; i < 2; ++i) {
    int e = tid + i * 256;                 // (b*16+q)*4+c
    int c = e & 3, q = (e >> 2) & 15, b = e >> 6;
    float s = 0.f;
    #pragma unroll
    for (int r = 0; r < 16; ++r)
      s += f1[((b * 16 + q) * 16 + r) * 8 + y] * lf[(c * 16 + r) * 8 + z];
    gs[e] = s;
  }
  __syncthreads();
  #pragma unroll
  for (int j = 0; j < 4; ++j) {
    int k = tid + j * 256;
    int p = k & 3, c = (k >> 2) & 3, b = (k >> 4) & 7, a = k >> 7;
    float s = 0.f;
    #pragma unroll
    for (int q = 0; q < 16; ++q)
      s += f0[((a * 4 + p) * 16 + q) * 8 + x] * gs[(b * 16 + q) * 4 + c];
    chainT[(size_t)o * 1024 + k] = f2bf(s);
  }
}

// ---------------- depthwise 3x3 conv -> t[m][k] bf16 (K-contiguous)
// block = (n, h-quad, channel-quarter). grid = 32*8*4 = 1024 blocks.
__global__ __launch_bounds__(256) void conv_kernel(const float* __restrict__ in,
                                                   const float* __restrict__ sf,
                                                   ushort_t* __restrict__ t) {
  __shared__ float in_lds[64][244];
  __shared__ float sf_l[36];
  int bid = blockIdx.x;
  int cq = bid & 3, h4 = (bid >> 2) & 7, n = bid >> 5;
  int h0 = h4 * 4;
  int tid = threadIdx.x;
  if (tid < 36) sf_l[tid] = sf[tid];
  for (int e = tid; e < 384; e += 256) {
    int ch = e / 6, r = e % 6;
    in_lds[ch][r * 40 + 3] = 0.f;
    in_lds[ch][r * 40 + 36] = 0.f;
  }
  const float* inb = in + ((size_t)n * 256 + cq * 64) * 1024;
  #pragma unroll
  for (int i = 0; i < 12; ++i) {
    int e = tid + i * 256;
    int ch = e / 48, rem = e % 48;
    int r = rem >> 3, w4 = rem & 7;
    int hh = h0 - 1 + r;
    float4 v = make_float4(0.f, 0.f, 0.f, 0.f);
    if (hh >= 0 && hh < 32)
      v = *(const float4*)&inb[(size_t)ch * 1024 + hh * 32 + w4 * 4];
    *(float4*)&in_lds[ch][r * 40 + 4 + w4 * 4] = v;
  }
  __syncthreads();
  float sfr[36];
  #pragma unroll
  for (int i = 0; i < 36; ++i) sfr[i] = sf_l[i];
  int w = tid >> 3, gg = tid & 7;
  size_t m0 = (size_t)n * 1024 + (size_t)h0 * 32 + w;
  #pragma unroll
  for (int j = 0; j < 4; ++j) {
    float acc[4][2][4];
    #pragma unroll
    for (int b = 0; b < 2; ++b) {
      int ch = j * 16 + gg * 2 + b;
      float vals[6][3];
      #pragma unroll
      for (int r = 0; r < 6; ++r)
        #pragma unroll
        for (int dw = 0; dw < 3; ++dw)
          vals[r][dw] = in_lds[ch][r * 40 + 3 + w + dw];
      #pragma unroll
      for (int hh = 0; hh < 4; ++hh)
        #pragma unroll
        for (int p = 0; p < 4; ++p) {
          float s = 0.f;
          #pragma unroll
          for (int dr = 0; dr < 3; ++dr)
            #pragma unroll
            for (int dw = 0; dw < 3; ++dw)
              s += vals[hh + dr][dw] * sfr[p * 9 + dr * 3 + dw];
          acc[hh][b][p] = s;
        }
    }
    #pragma unroll
    for (int hh = 0; hh < 4; ++hh) {
      ushort8 outv;
      #pragma unroll
      for (int b = 0; b < 2; ++b)
        #pragma unroll
        for (int p = 0; p < 4; ++p) outv[b * 4 + p] = f2bf(acc[hh][b][p]);
      *(ushort8*)&t[(m0 + hh * 32) * 1024 + (size_t)(cq * 256 + j * 64 + gg * 8)] = outv;
    }
  }
}

// ---------------- GEMM: out[m][o] = sum_k t[m][k]*chainT[o][k] + bias[o]
// 256x256 tile, BK=64, 8 waves (2Mx4N), 8-phase, counted vmcnt, XOR-swizzle.
// SYNC (sound):
//  (RAW) producer-side VMCNT4 pre-closing-barrier at p3/p7 (retires the 8 loads
//        of the buffer about to be read; FIFO traced in comments below).
//  (WAR) reads of a buffer finish by p1/p5 (LGKMCNT0 before those closing
//        barriers); its re-stage is at p2/p3 / p6/p7 — >=1 closing barrier later.
// Reads are just-in-time (round-4 layout) to avoid over-waiting on LGKMCNT0.
#define AS1 __attribute__((address_space(1)))
#define AS3 __attribute__((address_space(3)))
#define BARRIER  __builtin_amdgcn_s_barrier()
#define LGKMCNT0 asm volatile("s_waitcnt lgkmcnt(0)" ::: "memory")
#define VMCNT4   asm volatile("s_waitcnt vmcnt(4)" ::: "memory")
#define VMCNT0   asm volatile("s_waitcnt vmcnt(0)" ::: "memory")

__global__ __launch_bounds__(512, 2) void gemm_kernel(const ushort_t* __restrict__ tA,
                                                      const ushort_t* __restrict__ tB,
                                                      const float* __restrict__ bias,
                                                      float* __restrict__ out) {
  __shared__ __align__(16) ushort_t smem[65536];   // 128 KB: As[2][16384] | Bs[2][16384]
  int tid = threadIdx.x;
  int bid = blockIdx.x;                            // 256 blocks
  int wg = (bid & 7) * 32 + (bid >> 3);            // bijective XCD swizzle (256%8==0)
  int tile_m = (wg >> 1) * 256;
  int tile_n = (wg & 1) * 256;

  int lane = tid & 63, wv = tid >> 6;
  int wm2 = wv >> 2, wn4 = wv & 3;
  int lr = lane & 15, kg = lane >> 4;
  int kph0 = ((kg * 8) ^ ((lane & 7) * 8));
  int kph1 = ((32 + kg * 8) ^ ((lane & 7) * 8));
  int arow = wm2 * 128 + lr;
  int brow = wn4 * 64 + lr;

  int srow = tid >> 3;
  int scol = ((tid & 7) ^ (srow & 7)) * 8;
  const ushort_t* sA = tA + (size_t)(tile_m + srow) * 1024 + scol;
  const ushort_t* sB = tB + (size_t)(tile_n + srow) * 1024 + scol;

#define STAGE_A(buf, koff, h)                                                                  \
  __builtin_amdgcn_global_load_lds((const AS1 void*)(sA + (size_t)((h)*128) * 1024 + (koff)),  \
      (AS3 void*)&smem[(buf)*16384 + (h)*8192 + tid*8], 16, 0, 0);                             \
  __builtin_amdgcn_global_load_lds((const AS1 void*)(sA + (size_t)((h)*128+64) * 1024 + (koff)),\
      (AS3 void*)&smem[(buf)*16384 + (h)*8192 + 4096 + tid*8], 16, 0, 0);
#define STAGE_B(buf, koff, h)                                                                  \
  __builtin_amdgcn_global_load_lds((const AS1 void*)(sB + (size_t)((h)*128) * 1024 + (koff)),  \
      (AS3 void*)&smem[32768 + (buf)*16384 + (h)*8192 + tid*8], 16, 0, 0);                     \
  __builtin_amdgcn_global_load_lds((const AS1 void*)(sB + (size_t)((h)*128+64) * 1024 + (koff)),\
      (AS3 void*)&smem[32768 + (buf)*16384 + (h)*8192 + 4096 + tid*8], 16, 0, 0);

#define READ_A(dst, mbase, buf)                                                                \
  _Pragma("unroll")                                                                            \
  for (int mf = 0; mf < 4; ++mf) {                                                             \
    dst[mf][0] = *(const bf16x8*)&smem[(buf)*16384 + (arow + (mbase) + mf*16)*64 + kph0];      \
    dst[mf][1] = *(const bf16x8*)&smem[(buf)*16384 + (arow + (mbase) + mf*16)*64 + kph1];      \
  }
#define READ_B(dst, nbase, buf)                                                                \
  _Pragma("unroll")                                                                            \
  for (int nf = 0; nf < 2; ++nf) {                                                             \
    dst[nf][0] = *(const bf16x8*)&smem[32768 + (buf)*16384 + (brow + (nbase) + nf*16)*64 + kph0];\
    dst[nf][1] = *(const bf16x8*)&smem[32768 + (buf)*16384 + (brow + (nbase) + nf*16)*64 + kph1];\
  }
#define Q_MFMA(AF, BF, MB, NB)                                                                 \
  __builtin_amdgcn_s_setprio(1);                                                              \
  _Pragma("unroll")                                                                            \
  for (int mf = 0; mf < 4; ++mf)                                                               \
    _Pragma("unroll")                                                                          \
    for (int nf = 0; nf < 2; ++nf)                                                             \
      _Pragma("unroll")                                                                        \
      for (int ks = 0; ks < 2; ++ks)                                                           \
        acc[(MB) + mf][(NB) + nf] = __builtin_amdgcn_mfma_f32_16x16x32_bf16(                   \
            AF[mf][ks], BF[nf][ks], acc[(MB) + mf][(NB) + nf], 0, 0, 0);                       \
  __builtin_amdgcn_s_setprio(0);

  f32x4 acc[8][4];
  #pragma unroll
  for (int i = 0; i < 8; ++i)
    #pragma unroll
    for (int j = 0; j < 4; ++j) acc[i][j] = (f32x4){0.f, 0.f, 0.f, 0.f};

  bf16x8 a1[4][2], a2[4][2], b1[2][2], b2[2][2];

  // prologue: kt0 (buf0) fully + kt1 A halves (buf1); VMCNT4 retires exactly
  // buf0's 8 loads producer-side BEFORE the barrier releases readers.
  STAGE_A(0, 0, 0) STAGE_A(0, 0, 1) STAGE_B(0, 0, 0) STAGE_B(0, 0, 1)
  STAGE_A(1, 64, 0) STAGE_A(1, 64, 1)
  VMCNT4; BARRIER;

  // FIFO at p3 VMCNT4: [A1k3(4, prev iter), B1k1(4), A0k2(4)] -> retires buf1's 8.
  // FIFO at p7 VMCNT4: [A0k2(4), B0k2(4), A1k3(4)]            -> retires buf0's 8.
#define ITER(I_, FULL)                                                                         \
  {                                                                                            \
    int k1 = (2*(I_)+1)*64, k2 = (2*(I_)+2)*64, k3 = (2*(I_)+3)*64;                            \
    /* p0: JIT reads a1,b1 (buf0 DMA certified by prev p7/prologue) */                         \
    READ_A(a1, 0, 0) READ_B(b1, 0, 0)                                                          \
    STAGE_B(1, k1, 0) BARRIER; LGKMCNT0;                                                       \
    Q_MFMA(a1, b1, 0, 0) BARRIER;                                                              \
    /* p1: remaining buf0 reads (b2,a2) — buf0 fully read after this phase */                  \
    READ_B(b2, 32, 0) READ_A(a2, 64, 0) STAGE_B(1, k1, 1) BARRIER; LGKMCNT0;                   \
    Q_MFMA(a1, b2, 0, 2) BARRIER;                                                              \
    /* p2: reg-only MFMA; A-buf0 re-stage is now safe */                                       \
    if (FULL) { STAGE_A(0, k2, 0) } BARRIER;                                                   \
    Q_MFMA(a2, b2, 4, 2) BARRIER;                                                              \
    /* p3: certify buf1 DMA pre-close */                                                       \
    if (FULL) { STAGE_A(0, k2, 1) } BARRIER;                                                   \
    Q_MFMA(a2, b1, 4, 0)                                                                       \
    if (FULL) { VMCNT4; } else { VMCNT0; }                                                     \
    BARRIER;                                                                                   \
    /* p4 */                                                                                   \
    READ_A(a1, 0, 1) READ_B(b1, 0, 1)                                                          \
    if (FULL) { STAGE_B(0, k2, 0) } BARRIER; LGKMCNT0;                                         \
    Q_MFMA(a1, b1, 0, 0) BARRIER;                                                              \
    /* p5 */                                                                                   \
    READ_B(b2, 32, 1) READ_A(a2, 64, 1)                                                        \
    if (FULL) { STAGE_B(0, k2, 1) } BARRIER; LGKMCNT0;                                         \
    Q_MFMA(a1, b2, 0, 2) BARRIER;                                                              \
    /* p6 */                                                                                   \
    if (FULL) { STAGE_A(1, k3, 0) } BARRIER;                                                   \
    Q_MFMA(a2, b2, 4, 2) BARRIER;                                                              \
    /* p7: certify next-iter buf0 DMA pre-close */                                             \
    if (FULL) { STAGE_A(1, k3, 1) } BARRIER;                                                   \
    Q_MFMA(a2, b1, 4, 0)                                                                       \
    if (FULL) { VMCNT4; }                                                                      \
    BARRIER;                                                                                   \
  }

  for (int I = 0; I < 7; ++I) ITER(I, 1)
  ITER(7, 0)
#undef ITER

  // epilogue: lane holds D[m=kg*4+r][o=lr] per 16x16 frag
  #pragma unroll
  for (int mf = 0; mf < 8; ++mf)
    #pragma unroll
    for (int nf = 0; nf < 4; ++nf) {
      int m = tile_m + wm2 * 128 + mf * 16 + kg * 4;
      int o = tile_n + wn4 * 64 + nf * 16 + lr;
      float bv = bias[o];
      f32x4 v = acc[mf][nf];
      v[0] += bv; v[1] += bv; v[2] += bv; v[3] += bv;
      *(f32x4*)&out[(size_t)(m >> 10) * 524288 + (size_t)o * 1024 + (size_t)(m & 1023)] = v;
    }
}

extern "C" void kernel_launch(void* const* d_in, const int* in_sizes, int n_in,
                              void* d_out, int out_size, void* d_ws, size_t ws_size,
                              hipStream_t stream) {
  (void)in_sizes; (void)n_in; (void)out_size; (void)ws_size;
  const float* in   = (const float*)d_in[0];
  const float* sf   = (const float*)d_in[1];
  const float* f0   = (const float*)d_in[2];
  const float* f1   = (const float*)d_in[3];
  const float* lf   = (const float*)d_in[4];
  const float* bias = (const float*)d_in[5];
  float* out = (float*)d_out;

  char* ws = (char*)d_ws;
  ushort_t* t      = (ushort_t*)ws;                          // 64 MB
  ushort_t* chainT = (ushort_t*)(ws + 67108864);             // 1 MB

  hipLaunchKernelGGL(chain_kernel, dim3(512),  dim3(256), 0, stream, f0, f1, lf, chainT);
  hipLaunchKernelGGL(conv_kernel,  dim3(1024), dim3(256), 0, stream, in, sf, t);
  hipLaunchKernelGGL(gemm_kernel,  dim3(256),  dim3(512), 0, stream, t, chainT, bias, out);
}

// Round 14
// 75.073 us; speedup vs baseline: 1.4570x; 1.0244x over previous
//
#include <hip/hip_runtime.h>

typedef unsigned short ushort_t;
typedef __attribute__((ext_vector_type(8))) short bf16x8;
typedef __attribute__((ext_vector_type(8))) unsigned short ushort8;
typedef __attribute__((ext_vector_type(4))) float f32x4;

__device__ __forceinline__ unsigned short f2bf(float f) {
  union { float f; unsigned u; } x; x.f = f;
  unsigned r = x.u + 0x7FFFu + ((x.u >> 16) & 1u);   // round-to-nearest-even
  return (unsigned short)(r >> 16);
}

// ---------------- fused chain: block = one o (512 blocks x 256 thr)
__global__ __launch_bounds__(256) void chain_kernel(const float* __restrict__ f0,
                                                    const float* __restrict__ f1,
                                                    const float* __restrict__ lf,
                                                    ushort_t* __restrict__ chainT) {
  __shared__ float gs[512];
  int o = blockIdx.x;
  int z = o & 7, y = (o >> 3) & 7, x = o >> 6;
  int tid = threadIdx.x;
  #pragma unroll
  for (int i = 0; i < 2; ++i) {
    int e = tid + i * 256;                 // (b*16+q)*4+c
    int c = e & 3, q = (e >> 2) & 15, b = e >> 6;
    float s = 0.f;
    #pragma unroll
    for (int r = 0; r < 16; ++r)
      s += f1[((b * 16 + q) * 16 + r) * 8 + y] * lf[(c * 16 + r) * 8 + z];
    gs[e] = s;
  }
  __syncthreads();
  #pragma unroll
  for (int j = 0; j < 4; ++j) {
    int k = tid + j * 256;
    int p = k & 3, c = (k >> 2) & 3, b = (k >> 4) & 7, a = k >> 7;
    float s = 0.f;
    #pragma unroll
    for (int q = 0; q < 16; ++q)
      s += f0[((a * 4 + p) * 16 + q) * 8 + x] * gs[(b * 16 + q) * 4 + c];
    chainT[(size_t)o * 1024 + k] = f2bf(s);
  }
}

// ---------------- depthwise 3x3 conv -> t[m][k] bf16 (K-contiguous)
__global__ __launch_bounds__(256) void conv_kernel(const float* __restrict__ in,
                                                   const float* __restrict__ sf,
                                                   ushort_t* __restrict__ t) {
  __shared__ float in_lds[64][244];
  __shared__ float sf_l[36];
  int bid = blockIdx.x;
  int cq = bid & 3, h4 = (bid >> 2) & 7, n = bid >> 5;
  int h0 = h4 * 4;
  int tid = threadIdx.x;
  if (tid < 36) sf_l[tid] = sf[tid];
  for (int e = tid; e < 384; e += 256) {
    int ch = e / 6, r = e % 6;
    in_lds[ch][r * 40 + 3] = 0.f;
    in_lds[ch][r * 40 + 36] = 0.f;
  }
  const float* inb = in + ((size_t)n * 256 + cq * 64) * 1024;
  #pragma unroll
  for (int i = 0; i < 12; ++i) {
    int e = tid + i * 256;
    int ch = e / 48, rem = e % 48;
    int r = rem >> 3, w4 = rem & 7;
    int hh = h0 - 1 + r;
    float4 v = make_float4(0.f, 0.f, 0.f, 0.f);
    if (hh >= 0 && hh < 32)
      v = *(const float4*)&inb[(size_t)ch * 1024 + hh * 32 + w4 * 4];
    *(float4*)&in_lds[ch][r * 40 + 4 + w4 * 4] = v;
  }
  __syncthreads();
  float sfr[36];
  #pragma unroll
  for (int i = 0; i < 36; ++i) sfr[i] = sf_l[i];
  int w = tid >> 3, gg = tid & 7;
  size_t m0 = (size_t)n * 1024 + (size_t)h0 * 32 + w;
  #pragma unroll
  for (int j = 0; j < 4; ++j) {
    float acc[4][2][4];
    #pragma unroll
    for (int b = 0; b < 2; ++b) {
      int ch = j * 16 + gg * 2 + b;
      float vals[6][3];
      #pragma unroll
      for (int r = 0; r < 6; ++r)
        #pragma unroll
        for (int dw = 0; dw < 3; ++dw)
          vals[r][dw] = in_lds[ch][r * 40 + 3 + w + dw];
      #pragma unroll
      for (int hh = 0; hh < 4; ++hh)
        #pragma unroll
        for (int p = 0; p < 4; ++p) {
          float s = 0.f;
          #pragma unroll
          for (int dr = 0; dr < 3; ++dr)
            #pragma unroll
            for (int dw = 0; dw < 3; ++dw)
              s += vals[hh + dr][dw] * sfr[p * 9 + dr * 3 + dw];
          acc[hh][b][p] = s;
        }
    }
    #pragma unroll
    for (int hh = 0; hh < 4; ++hh) {
      ushort8 outv;
      #pragma unroll
      for (int b = 0; b < 2; ++b)
        #pragma unroll
        for (int p = 0; p < 4; ++p) outv[b * 4 + p] = f2bf(acc[hh][b][p]);
      *(ushort8*)&t[(m0 + hh * 32) * 1024 + (size_t)(cq * 256 + j * 64 + gg * 8)] = outv;
    }
  }
}

// ---------------- GEMM: out[m][o] = sum_k t[m][k]*chainT[o][k] + bias[o]
// 256x256 tile, BK=64, 8 waves (2Mx4N), 8 phases with ONE barrier each.
// SYNC (sound, minimal):
//  (RAW LDS<-DMA) producer-side VMCNT4 pre-closing-barrier at p3/p7: FIFO at
//    p3 = [A1k3(4,prev), B1k1(4), A0k2(4)] -> retires buf1's 8;
//    p7 = [A0k2(4), B0k2(4), A1k3(4)]      -> retires buf0's 8. Tail: VMCNT0.
//  (WAR) every ds_read is serviced pre-closing-barrier: a1,b1,b2 via their
//    consuming MFMA's compiler-inserted lgkmcnt in the SAME phase; a2 (read p1,
//    consumed p2) via explicit LGKMCNT0 at end of p1/p5. Re-stages land >=1
//    closing barrier after the last serviced read of their region.
#define AS1 __attribute__((address_space(1)))
#define AS3 __attribute__((address_space(3)))
#define BARRIER  __builtin_amdgcn_s_barrier()
#define LGKMCNT0 asm volatile("s_waitcnt lgkmcnt(0)" ::: "memory")
#define VMCNT4   asm volatile("s_waitcnt vmcnt(4)" ::: "memory")
#define VMCNT0   asm volatile("s_waitcnt vmcnt(0)" ::: "memory")

__global__ __launch_bounds__(512, 2) void gemm_kernel(const ushort_t* __restrict__ tA,
                                                      const ushort_t* __restrict__ tB,
                                                      const float* __restrict__ bias,
                                                      float* __restrict__ out) {
  __shared__ __align__(16) ushort_t smem[65536];   // 128 KB: As[2][16384] | Bs[2][16384]
  int tid = threadIdx.x;
  int bid = blockIdx.x;                            // 256 blocks
  int wg = (bid & 7) * 32 + (bid >> 3);            // bijective XCD swizzle (256%8==0)
  int tile_m = (wg >> 1) * 256;
  int tile_n = (wg & 1) * 256;

  int lane = tid & 63, wv = tid >> 6;
  int wm2 = wv >> 2, wn4 = wv & 3;
  int lr = lane & 15, kg = lane >> 4;
  int kph0 = ((kg * 8) ^ ((lane & 7) * 8));
  int kph1 = ((32 + kg * 8) ^ ((lane & 7) * 8));
  int arow = wm2 * 128 + lr;
  int brow = wn4 * 64 + lr;

  int srow = tid >> 3;
  int scol = ((tid & 7) ^ (srow & 7)) * 8;
  const ushort_t* sA = tA + (size_t)(tile_m + srow) * 1024 + scol;
  const ushort_t* sB = tB + (size_t)(tile_n + srow) * 1024 + scol;

#define STAGE_A(buf, koff, h)                                                                  \
  __builtin_amdgcn_global_load_lds((const AS1 void*)(sA + (size_t)((h)*128) * 1024 + (koff)),  \
      (AS3 void*)&smem[(buf)*16384 + (h)*8192 + tid*8], 16, 0, 0);                             \
  __builtin_amdgcn_global_load_lds((const AS1 void*)(sA + (size_t)((h)*128+64) * 1024 + (koff)),\
      (AS3 void*)&smem[(buf)*16384 + (h)*8192 + 4096 + tid*8], 16, 0, 0);
#define STAGE_B(buf, koff, h)                                                                  \
  __builtin_amdgcn_global_load_lds((const AS1 void*)(sB + (size_t)((h)*128) * 1024 + (koff)),  \
      (AS3 void*)&smem[32768 + (buf)*16384 + (h)*8192 + tid*8], 16, 0, 0);                     \
  __builtin_amdgcn_global_load_lds((const AS1 void*)(sB + (size_t)((h)*128+64) * 1024 + (koff)),\
      (AS3 void*)&smem[32768 + (buf)*16384 + (h)*8192 + 4096 + tid*8], 16, 0, 0);

#define READ_A(dst, mbase, buf)                                                                \
  _Pragma("unroll")                                                                            \
  for (int mf = 0; mf < 4; ++mf) {                                                             \
    dst[mf][0] = *(const bf16x8*)&smem[(buf)*16384 + (arow + (mbase) + mf*16)*64 + kph0];      \
    dst[mf][1] = *(const bf16x8*)&smem[(buf)*16384 + (arow + (mbase) + mf*16)*64 + kph1];      \
  }
#define READ_B(dst, nbase, buf)                                                                \
  _Pragma("unroll")                                                                            \
  for (int nf = 0; nf < 2; ++nf) {                                                             \
    dst[nf][0] = *(const bf16x8*)&smem[32768 + (buf)*16384 + (brow + (nbase) + nf*16)*64 + kph0];\
    dst[nf][1] = *(const bf16x8*)&smem[32768 + (buf)*16384 + (brow + (nbase) + nf*16)*64 + kph1];\
  }
#define Q_MFMA(AF, BF, MB, NB)                                                                 \
  __builtin_amdgcn_s_setprio(1);                                                              \
  _Pragma("unroll")                                                                            \
  for (int mf = 0; mf < 4; ++mf)                                                               \
    _Pragma("unroll")                                                                          \
    for (int nf = 0; nf < 2; ++nf)                                                             \
      _Pragma("unroll")                                                                        \
      for (int ks = 0; ks < 2; ++ks)                                                           \
        acc[(MB) + mf][(NB) + nf] = __builtin_amdgcn_mfma_f32_16x16x32_bf16(                   \
            AF[mf][ks], BF[nf][ks], acc[(MB) + mf][(NB) + nf], 0, 0, 0);                       \
  __builtin_amdgcn_s_setprio(0);

  f32x4 acc[8][4];
  #pragma unroll
  for (int i = 0; i < 8; ++i)
    #pragma unroll
    for (int j = 0; j < 4; ++j) acc[i][j] = (f32x4){0.f, 0.f, 0.f, 0.f};

  bf16x8 a1[4][2], a2[4][2], b1[2][2], b2[2][2];

  // prologue: kt0 (buf0) fully + kt1 A halves (buf1); VMCNT4 retires exactly
  // buf0's 8 loads producer-side BEFORE the barrier releases readers.
  STAGE_A(0, 0, 0) STAGE_A(0, 0, 1) STAGE_B(0, 0, 0) STAGE_B(0, 0, 1)
  STAGE_A(1, 64, 0) STAGE_A(1, 64, 1)
  VMCNT4; BARRIER;

#define ITER(I_, FULL)                                                                         \
  {                                                                                            \
    int k1 = (2*(I_)+1)*64, k2 = (2*(I_)+2)*64, k3 = (2*(I_)+3)*64;                            \
    /* p0: reads a1,b1 (serviced by MFMA wait); stage B-buf1 h0 in flight */                   \
    READ_A(a1, 0, 0) READ_B(b1, 0, 0)                                                          \
    STAGE_B(1, k1, 0)                                                                          \
    Q_MFMA(a1, b1, 0, 0) BARRIER;                                                              \
    /* p1: reads b2 (serviced by MFMA), a2 (forced by LGKMCNT0) */                             \
    READ_B(b2, 32, 0) READ_A(a2, 64, 0)                                                        \
    STAGE_B(1, k1, 1)                                                                          \
    Q_MFMA(a1, b2, 0, 2) LGKMCNT0; BARRIER;                                                    \
    /* p2: A-buf0 re-stage (all buf0-A reads serviced by p1's barrier) */                      \
    if (FULL) { STAGE_A(0, k2, 0) }                                                            \
    Q_MFMA(a2, b2, 4, 2) BARRIER;                                                              \
    /* p3: certify buf1 DMA (A1k3-prev + B1k1) pre-close */                                    \
    if (FULL) { STAGE_A(0, k2, 1) }                                                            \
    Q_MFMA(a2, b1, 4, 0)                                                                       \
    if (FULL) { VMCNT4; } else { VMCNT0; }                                                     \
    BARRIER;                                                                                   \
    /* p4 */                                                                                   \
    READ_A(a1, 0, 1) READ_B(b1, 0, 1)                                                          \
    if (FULL) { STAGE_B(0, k2, 0) }                                                            \
    Q_MFMA(a1, b1, 0, 0) BARRIER;                                                              \
    /* p5 */                                                                                   \
    READ_B(b2, 32, 1) READ_A(a2, 64, 1)                                                        \
    if (FULL) { STAGE_B(0, k2, 1) }                                                            \
    Q_MFMA(a1, b2, 0, 2) LGKMCNT0; BARRIER;                                                    \
    /* p6 */                                                                                   \
    if (FULL) { STAGE_A(1, k3, 0) }                                                            \
    Q_MFMA(a2, b2, 4, 2) BARRIER;                                                              \
    /* p7: certify next-iter buf0 DMA (A0k2 + B0k2) pre-close */                               \
    if (FULL) { STAGE_A(1, k3, 1) }                                                            \
    Q_MFMA(a2, b1, 4, 0)                                                                       \
    if (FULL) { VMCNT4; }                                                                      \
    BARRIER;                                                                                   \
  }

  for (int I = 0; I < 7; ++I) ITER(I, 1)
  ITER(7, 0)
#undef ITER

  // epilogue: lane holds D[m=kg*4+r][o=lr] per 16x16 frag
  #pragma unroll
  for (int mf = 0; mf < 8; ++mf)
    #pragma unroll
    for (int nf = 0; nf < 4; ++nf) {
      int m = tile_m + wm2 * 128 + mf * 16 + kg * 4;
      int o = tile_n + wn4 * 64 + nf * 16 + lr;
      float bv = bias[o];
      f32x4 v = acc[mf][nf];
      v[0] += bv; v[1] += bv; v[2] += bv; v[3] += bv;
      *(f32x4*)&out[(size_t)(m >> 10) * 524288 + (size_t)o * 1024 + (size_t)(m & 1023)] = v;
    }
}

extern "C" void kernel_launch(void* const* d_in, const int* in_sizes, int n_in,
                              void* d_out, int out_size, void* d_ws, size_t ws_size,
                              hipStream_t stream) {
  (void)in_sizes; (void)n_in; (void)out_size; (void)ws_size;
  const float* in   = (const float*)d_in[0];
  const float* sf   = (const float*)d_in[1];
  const float* f0   = (const float*)d_in[2];
  const float* f1   = (const float*)d_in[3];
  const float* lf   = (const float*)d_in[4];
  const float* bias = (const float*)d_in[5];
  float* out = (float*)d_out;

  char* ws = (char*)d_ws;
  ushort_t* t      = (ushort_t*)ws;                          // 64 MB
  ushort_t* chainT = (ushort_t*)(ws + 67108864);             // 1 MB

  hipLaunchKernelGGL(chain_kernel, dim3(512),  dim3(256), 0, stream, f0, f1, lf, chainT);
  hipLaunchKernelGGL(conv_kernel,  dim3(1024), dim3(256), 0, stream, in, sf, t);
  hipLaunchKernelGGL(gemm_kernel,  dim3(256),  dim3(512), 0, stream, t, chainT, bias, out);
}